// Round 10
// baseline (747.604 us; speedup 1.0000x reference)
//
#include <hip/hip_runtime.h>
#include <hip/hip_bf16.h>

#define BATCH   16
#define NPTS    2048
#define NPOINT  512
#define CFEAT   128
#define CIN     131
#define CMID    32
#define NS_TOT  96

typedef float v2f __attribute__((ext_vector_type(2)));

// exact (non-contracted) squared distance, matching jnp's ((dx^2+dy^2)+dz^2)
__device__ __forceinline__ float d2_rn(float ax, float ay, float az,
                                       float bx, float by, float bz) {
  float dx = __fsub_rn(ax, bx), dy = __fsub_rn(ay, by), dz = __fsub_rn(az, bz);
  return __fadd_rn(__fadd_rn(__fmul_rn(dx, dx), __fmul_rn(dy, dy)), __fmul_rn(dz, dz));
}

// 64-bit packed-key wave max via DPP on both halves; result broadcast to all
// lanes via readlane(63). Key = (dist_bits << 32) | (0xFFF - n):
// max by distance, then smallest index n on ties — matches jnp argmax.
__device__ __forceinline__ unsigned long long wave_kmax64_bcast(unsigned long long k) {
#define KSTEP(CTRL, RMASK, BMASK)                                              \
  {                                                                            \
    unsigned hi = (unsigned)(k >> 32), lo = (unsigned)k;                       \
    unsigned thi = (unsigned)__builtin_amdgcn_update_dpp(                      \
        (int)hi, (int)hi, CTRL, RMASK, BMASK, false);                          \
    unsigned tlo = (unsigned)__builtin_amdgcn_update_dpp(                      \
        (int)lo, (int)lo, CTRL, RMASK, BMASK, false);                          \
    unsigned long long tk = ((unsigned long long)thi << 32) | tlo;             \
    k = tk > k ? tk : k;                                                       \
  }
  KSTEP(0x111, 0xf, 0xf)  // row_shr:1
  KSTEP(0x112, 0xf, 0xf)  // row_shr:2
  KSTEP(0x114, 0xf, 0xe)  // row_shr:4
  KSTEP(0x118, 0xf, 0xc)  // row_shr:8
  KSTEP(0x142, 0xa, 0xf)  // row_bcast:15
  KSTEP(0x143, 0xc, 0xf)  // row_bcast:31
#undef KSTEP
  unsigned bh = (unsigned)__builtin_amdgcn_readlane((int)(unsigned)(k >> 32), 63);
  unsigned bl = (unsigned)__builtin_amdgcn_readlane((int)(unsigned)k, 63);
  return ((unsigned long long)bh << 32) | bl;
}

// blocks [0,16): FPS per batch; blocks [16, 16+4096): transpose features -> featT
__global__ __launch_bounds__(256) void fps_transpose_kernel(
    const float* __restrict__ xyz, const float* __restrict__ feat,
    float* __restrict__ featT, float* __restrict__ out_xyz)
{
  int t = threadIdx.x;
  if (blockIdx.x >= BATCH) {
    __shared__ float tile[32][33];
    int m  = blockIdx.x - BATCH;
    int b  = m >> 8;
    int c0 = ((m >> 6) & 3) << 5;
    int n0 = (m & 63) << 5;
    int tx = t & 31, ty = t >> 5;
    const float* src = feat  + (size_t)b * CFEAT * NPTS;
    float*       dst = featT + (size_t)b * NPTS * CFEAT;
#pragma unroll
    for (int i = 0; i < 4; ++i)
      tile[ty + 8 * i][tx] = src[(size_t)(c0 + ty + 8 * i) * NPTS + n0 + tx];
    __syncthreads();
#pragma unroll
    for (int i = 0; i < 4; ++i)
      dst[(size_t)(n0 + ty + 8 * i) * CFEAT + c0 + tx] = tile[tx][ty + 8 * i];
    return;
  }
  // ---- FPS: one block per batch, 256 threads (4 waves), 8 pts/thread.
  // Per step: tournament-select per-lane winner (val, lo, x, y, z) with
  // compile-time indexing; 64-bit DPP wave max broadcast via readlane; the
  // unique winning lane publishes (key, coords) to LDS; after ONE barrier all
  // lanes read the 4 records in parallel and cndmask-select next pv — no
  // dependent sp[last] round trip. No global ops inside the loop.
  __shared__ float4 sp[NPTS];                         // 32 KB (init + flush)
  __shared__ __align__(16) unsigned long long skey[2][4];
  __shared__ __align__(16) float4 srec[2][4];         // winner coords per wave
  __shared__ int slast[NPOINT];                       // 2 KB
  int b = blockIdx.x;
  const float* xb = xyz + (size_t)b * NPTS * 3;
  for (int n = t; n < NPTS; n += 256) {
    const float* p = xb + n * 3;
    sp[n] = make_float4(p[0], p[1], p[2], 0.f);
  }
  if (t == 0) slast[0] = 0;
  __syncthreads();
  float lx[8], ly[8], lz[8], d[8];
#pragma unroll
  for (int i = 0; i < 8; ++i) {
    float4 q = sp[(i << 8) + t];
    lx[i] = q.x; ly[i] = q.y; lz[i] = q.z;
    d[i] = 1e10f;
  }
  float4 p0v = sp[0];
  float pvx = p0v.x, pvy = p0v.y, pvz = p0v.z;
  int w = t >> 6;
  unsigned tb = 0xFFFu - (unsigned)t;
#pragma unroll 1
  for (int step = 1; step < NPOINT; ++step) {
    float nd[8];
#pragma unroll
    for (int i = 0; i < 8; ++i) {
      float dd = d2_rn(lx[i], ly[i], lz[i], pvx, pvy, pvz);
      float m = fminf(d[i], dd);
      d[i] = m; nd[i] = m;
    }
    // tournament (strict >, left wins ties == ascending scan with strict >)
    float tv[4], tx4[4], ty4[4], tz4[4]; unsigned tl[4];
#pragma unroll
    for (int q = 0; q < 4; ++q) {
      bool s = nd[2 * q + 1] > nd[2 * q];
      tv[q]  = s ? nd[2 * q + 1] : nd[2 * q];
      tl[q]  = s ? (tb - (unsigned)((2 * q + 1) << 8))
                 : (tb - (unsigned)((2 * q) << 8));
      tx4[q] = s ? lx[2 * q + 1] : lx[2 * q];
      ty4[q] = s ? ly[2 * q + 1] : ly[2 * q];
      tz4[q] = s ? lz[2 * q + 1] : lz[2 * q];
    }
    bool sA = tv[1] > tv[0];
    float vA = sA ? tv[1] : tv[0];   unsigned lA = sA ? tl[1] : tl[0];
    float xA = sA ? tx4[1] : tx4[0]; float yA = sA ? ty4[1] : ty4[0];
    float zA = sA ? tz4[1] : tz4[0];
    bool sB = tv[3] > tv[2];
    float vB = sB ? tv[3] : tv[2];   unsigned lB = sB ? tl[3] : tl[2];
    float xB = sB ? tx4[3] : tx4[2]; float yB = sB ? ty4[3] : ty4[2];
    float zB = sB ? tz4[3] : tz4[2];
    bool sC = vB > vA;
    float fv = sC ? vB : vA;         unsigned fl = sC ? lB : lA;
    float fx = sC ? xB : xA; float fy = sC ? yB : yA; float fz = sC ? zB : zA;
    unsigned long long best =
        ((unsigned long long)__float_as_uint(fv) << 32) | fl;
    unsigned long long wk = wave_kmax64_bcast(best);
    int par = step & 1;
    if (best == wk) {   // exactly one lane per wave (keys globally unique)
      skey[par][w] = wk;
      srec[par][w] = make_float4(fx, fy, fz, 0.f);
    }
    __syncthreads();
    const ulonglong2* kp = (const ulonglong2*)&skey[par][0];
    ulonglong2 kA2 = kp[0], kB2 = kp[1];
    float4 r0 = srec[par][0], r1 = srec[par][1];
    float4 r2 = srec[par][2], r3 = srec[par][3];
    unsigned long long k0 = kA2.x, k1 = kA2.y, k2 = kB2.x, k3 = kB2.y;
    bool s01 = k1 > k0;
    unsigned long long ka = s01 ? k1 : k0;
    float ax = s01 ? r1.x : r0.x, ay = s01 ? r1.y : r0.y, az = s01 ? r1.z : r0.z;
    bool s23 = k3 > k2;
    unsigned long long kb = s23 ? k3 : k2;
    float bx = s23 ? r3.x : r2.x, by = s23 ? r3.y : r2.y, bz = s23 ? r3.z : r2.z;
    bool sab = kb > ka;
    unsigned long long km = sab ? kb : ka;
    pvx = sab ? bx : ax; pvy = sab ? by : ay; pvz = sab ? bz : az;
    int last = (int)((0xFFFu - ((unsigned)km & 0xFFFu)) & (NPTS - 1));
    if (t == 0) slast[step] = last;
  }
  __syncthreads();
  for (int s = t; s < NPOINT; s += 256) {
    float4 q = sp[slast[s]];
    float* o = out_xyz + ((size_t)b * NPOINT + s) * 3;
    o[0] = q.x; o[1] = q.y; o[2] = q.z;
  }
}

// one block per (center j, batch b): ball query (3 radii) + MLP + maxpool + GEMM
// out_tmp != nullptr: write (b, j, 384) coalesced; else legacy strided writes.
__global__ __launch_bounds__(128, 4) void center_kernel(
    const float* __restrict__ xyz, const float* __restrict__ featT,
    const float* __restrict__ W1, const float* __restrict__ b1,
    const float* __restrict__ W2, const float* __restrict__ b2,
    const float* __restrict__ Wcr, const float* __restrict__ bcr,
    const float* __restrict__ new_xyz, float* __restrict__ out_feat,
    float* __restrict__ out_tmp)
{
  int j = blockIdx.x, b = blockIdx.y, t = threadIdx.x;
  __shared__ int   sIdx[NS_TOT];
  __shared__ __align__(16) float sH1[NS_TOT * 36];   // stride 36: 16B rows
  __shared__ float sVr[NS_TOT * 4];                  // relu(h2_c * rel_c), c<3
  __shared__ __align__(16) float sPooled[3 * 132];

  float cx = new_xyz[((size_t)b * NPOINT + j) * 3 + 0];
  float cy = new_xyz[((size_t)b * NPOINT + j) * 3 + 1];
  float cz = new_xyz[((size_t)b * NPOINT + j) * 3 + 2];

  // ---- ball query: wave 0 -> r0,r1 ; wave 1 -> r2. Ascending index order. ----
  {
    int w = t >> 6, lane = t & 63;
    const float* xb = xyz + (size_t)b * NPTS * 3;
    unsigned long long lt = (1ull << lane) - 1ull;
    if (w == 0) {
      int c0 = 0, c1 = 0;
      for (int it = 0; it < 32; ++it) {
        int n = (it << 6) + lane;
        float px = xb[n * 3 + 0], py = xb[n * 3 + 1], pz = xb[n * 3 + 2];
        float d2 = d2_rn(cx, cy, cz, px, py, pz);
        bool i0 = d2 < 0.01f, i1 = d2 < 0.04f;
        unsigned long long m0 = __ballot(i0), m1 = __ballot(i1);
        if (i0) { int pos = c0 + __popcll(m0 & lt); if (pos < 16) sIdx[pos] = n; }
        if (i1) { int pos = c1 + __popcll(m1 & lt); if (pos < 32) sIdx[16 + pos] = n; }
        c0 += __popcll(m0); c1 += __popcll(m1);
        if (c0 >= 16 && c1 >= 32) break;
      }
      int f0 = sIdx[0];
      int f1 = sIdx[16];
      if (lane >= c0 && lane < 16) sIdx[lane] = f0;
      if (lane >= c1 && lane < 32) sIdx[16 + lane] = f1;
    } else {
      int c2 = 0;
      for (int it = 0; it < 32; ++it) {
        int n = (it << 6) + lane;
        float px = xb[n * 3 + 0], py = xb[n * 3 + 1], pz = xb[n * 3 + 2];
        float d2 = d2_rn(cx, cy, cz, px, py, pz);
        bool i2 = d2 < 0.16f;
        unsigned long long m2 = __ballot(i2);
        if (i2) { int pos = c2 + __popcll(m2 & lt); if (pos < 48) sIdx[48 + pos] = n; }
        c2 += __popcll(m2);
        if (c2 >= 48) break;
      }
      int f2 = sIdx[48];
      if (lane >= c2 && lane < 48) sIdx[48 + lane] = f2;
    }
  }
  __syncthreads();

  // ---- h1 = relu(h10 @ W1 + b1), packed channel pairs (exact per-channel
  // chain); also rel channels' relu(h2_c * rel_c) ----
  if (t < NS_TOT) {
    int idx = sIdx[t];
    const float* p = xyz + ((size_t)b * NPTS + (size_t)idx) * 3;
    float px = p[0], py = p[1], pz = p[2];
    float rx = __fsub_rn(px, cx), ry = __fsub_rn(py, cy), rz = __fsub_rn(pz, cz);
    float dist = sqrtf(__fadd_rn(__fadd_rn(__fmul_rn(rx, rx), __fmul_rn(ry, ry)),
                                 __fmul_rn(rz, rz)));
    float h10[10] = {dist, cx, cy, cz, px, py, pz, rx, ry, rz};
    float h1r[CMID];
#pragma unroll
    for (int m = 0; m < CMID / 2; ++m) {
      v2f a = { b1[2 * m], b1[2 * m + 1] };
#pragma unroll
      for (int i = 0; i < 10; ++i) {
        v2f wv = { W1[i * CMID + 2 * m], W1[i * CMID + 2 * m + 1] };
        v2f hv = { h10[i], h10[i] };
        a = __builtin_elementwise_fma(hv, wv, a);
      }
      v2f z = { 0.f, 0.f };
      a = __builtin_elementwise_max(a, z);
      h1r[2 * m] = a.x; h1r[2 * m + 1] = a.y;
    }
#pragma unroll
    for (int q = 0; q < 8; ++q)
      *(float4*)&sH1[t * 36 + 4 * q] = *(const float4*)&h1r[4 * q];
    v2f pa0 = { b2[0], 0.f }, pa1 = { b2[1], 0.f }, pa2 = { b2[2], 0.f };
#pragma unroll
    for (int m = 0; m < CMID / 2; ++m) {
      v2f hv = { h1r[2 * m], h1r[2 * m + 1] };
      v2f w0 = { W2[(2 * m) * CIN + 0], W2[(2 * m + 1) * CIN + 0] };
      v2f w1 = { W2[(2 * m) * CIN + 1], W2[(2 * m + 1) * CIN + 1] };
      v2f w2 = { W2[(2 * m) * CIN + 2], W2[(2 * m + 1) * CIN + 2] };
      pa0 = __builtin_elementwise_fma(hv, w0, pa0);
      pa1 = __builtin_elementwise_fma(hv, w1, pa1);
      pa2 = __builtin_elementwise_fma(hv, w2, pa2);
    }
    float a0 = __fadd_rn(pa0.x, pa0.y);
    float a1 = __fadd_rn(pa1.x, pa1.y);
    float a2 = __fadd_rn(pa2.x, pa2.y);
    sVr[t * 4 + 0] = fmaxf(__fmul_rn(a0, rx), 0.f);
    sVr[t * 4 + 1] = fmaxf(__fmul_rn(a1, ry), 0.f);
    sVr[t * 4 + 2] = fmaxf(__fmul_rn(a2, rz), 0.f);
  }
  __syncthreads();

  // ---- feature channels, s-split: wave0 -> samples 0..47 (r0,r1), wave1 ->
  // samples 48..95 (r2). Each lane covers channels (lane, lane+64).
  // unroll 2: double the outstanding featT gathers (latency cover). ----
  {
    int w = t >> 6, lane = t & 63;
    v2f wA[16], wB[16];
#pragma unroll
    for (int m = 0; m < 16; ++m) {
      wA[m] = (v2f){ W2[(2 * m) * CIN + 3 + lane],
                     W2[(2 * m + 1) * CIN + 3 + lane] };
      wB[m] = (v2f){ W2[(2 * m) * CIN + 3 + lane + 64],
                     W2[(2 * m + 1) * CIN + 3 + lane + 64] };
    }
    float bA = b2[3 + lane], bB = b2[3 + lane + 64];
    const float* ftb = featT + (size_t)b * NPTS * CFEAT;
    int sBeg = w ? 48 : 0;
    int sEnd = w ? 96 : 48;
    int sMid = w ? 10000 : 16;   // wave0 stores r0 row after s==15
    float xA0 = ftb[(size_t)sIdx[sBeg] * CFEAT + lane];
    float xB0 = ftb[(size_t)sIdx[sBeg] * CFEAT + lane + 64];
    float xA1 = ftb[(size_t)sIdx[sBeg + 1] * CFEAT + lane];
    float xB1 = ftb[(size_t)sIdx[sBeg + 1] * CFEAT + lane + 64];
    float plA = 0.f, plB = 0.f;
#pragma unroll 2
    for (int s = sBeg; s < sEnd; ++s) {
      int sp2 = (s + 2 < sEnd) ? s + 2 : sEnd - 1;
      float xA2 = ftb[(size_t)sIdx[sp2] * CFEAT + lane];
      float xB2 = ftb[(size_t)sIdx[sp2] * CFEAT + lane + 64];
      const float4* h4 = (const float4*)&sH1[s * 36];
      v2f aAA = (v2f){ bA, 0.f }, aAB = (v2f){ 0.f, 0.f };
      v2f aBA = (v2f){ bB, 0.f }, aBB = (v2f){ 0.f, 0.f };
#pragma unroll
      for (int q = 0; q < 8; ++q) {
        float4 h = h4[q];
        v2f hxy = (v2f){ h.x, h.y }, hzw = (v2f){ h.z, h.w };
        aAA = __builtin_elementwise_fma(hxy, wA[2 * q],     aAA);
        aAB = __builtin_elementwise_fma(hzw, wA[2 * q + 1], aAB);
        aBA = __builtin_elementwise_fma(hxy, wB[2 * q],     aBA);
        aBB = __builtin_elementwise_fma(hzw, wB[2 * q + 1], aBB);
      }
      float hA = __fadd_rn(__fadd_rn(aAA.x, aAA.y), __fadd_rn(aAB.x, aAB.y));
      float hB = __fadd_rn(__fadd_rn(aBA.x, aBA.y), __fadd_rn(aBB.x, aBB.y));
      plA = fmaxf(plA, fmaxf(__fmul_rn(hA, xA0), 0.f));
      plB = fmaxf(plB, fmaxf(__fmul_rn(hB, xB0), 0.f));
      xA0 = xA1; xA1 = xA2; xB0 = xB1; xB1 = xB2;
      if (s + 1 == sMid) {   // wave0 only: end of r0 segment
        sPooled[0 * 132 + 3 + lane]      = plA;
        sPooled[0 * 132 + 3 + lane + 64] = plB;
        plA = 0.f; plB = 0.f;
      }
    }
    int rowL = w ? 2 : 1;
    sPooled[rowL * 132 + 3 + lane]      = plA;
    sPooled[rowL * 132 + 3 + lane + 64] = plB;
  }
  // ---- rel channels (0..2): segment max over sVr, threads 0..8 ----
  if (t < 9) {
    int r = t / 3, c = t - r * 3;
    int s0 = (r == 0) ? 0 : (r == 1 ? 16 : 48);
    int s1 = (r == 0) ? 16 : (r == 1 ? 48 : 96);
    float pl = 0.f;
    for (int s = s0; s < s1; ++s) pl = fmaxf(pl, sVr[s * 4 + c]);
    sPooled[r * 132 + c] = pl;
  }
  __syncthreads();

  // ---- out = relu(pooled @ Wcr + bcr): radii 0,1 packed, radius 2 scalar.
  // unroll 2: double the outstanding Wcr loads. ----
  v2f s01 = { bcr[t], bcr[t] };
  float s2 = bcr[t];
#pragma unroll 2
  for (int k4 = 0; k4 < 128; k4 += 4) {
    float4 p0 = *(const float4*)&sPooled[k4];
    float4 p1 = *(const float4*)&sPooled[132 + k4];
    float4 p2 = *(const float4*)&sPooled[264 + k4];
#pragma unroll
    for (int u = 0; u < 4; ++u) {
      float w = Wcr[(k4 + u) * CFEAT + t];
      float e0 = (&p0.x)[u], e1 = (&p1.x)[u], e2 = (&p2.x)[u];
      s01 = __builtin_elementwise_fma((v2f){ e0, e1 }, (v2f){ w, w }, s01);
      s2  = fmaf(e2, w, s2);
    }
  }
#pragma unroll
  for (int k = 128; k < CIN; ++k) {
    float w = Wcr[k * CFEAT + t];
    s01 = __builtin_elementwise_fma((v2f){ sPooled[k], sPooled[132 + k] },
                                    (v2f){ w, w }, s01);
    s2  = fmaf(sPooled[264 + k], w, s2);
  }
  if (out_tmp) {
    // coalesced: (b, j, c) with c = r*128 + t -> 3 contiguous 512B stores
    float* ob = out_tmp + ((size_t)b * NPOINT + j) * 384;
    ob[t]       = fmaxf(s01.x, 0.f);
    ob[128 + t] = fmaxf(s01.y, 0.f);
    ob[256 + t] = fmaxf(s2, 0.f);
  } else {
    float* ob = out_feat + (size_t)b * 384 * NPOINT + j;
    ob[(size_t)(0 * CFEAT + t) * NPOINT] = fmaxf(s01.x, 0.f);
    ob[(size_t)(1 * CFEAT + t) * NPOINT] = fmaxf(s01.y, 0.f);
    ob[(size_t)(2 * CFEAT + t) * NPOINT] = fmaxf(s2, 0.f);
  }
}

// tmp (b, j, 384) -> out_feat (b, 384, j): 32x32 LDS tile, both sides coalesced
__global__ __launch_bounds__(256) void untranspose_kernel(
    const float* __restrict__ tmp, float* __restrict__ out_feat)
{
  __shared__ float tile[32][33];
  int jt = blockIdx.x, ct = blockIdx.y, b = blockIdx.z;
  int t = threadIdx.x, tx = t & 31, ty = t >> 5;
  const float* src = tmp      + (size_t)b * NPOINT * 384;
  float*       dst = out_feat + (size_t)b * 384 * NPOINT;
#pragma unroll
  for (int i = 0; i < 4; ++i)
    tile[ty + 8 * i][tx] = src[(size_t)(jt * 32 + ty + 8 * i) * 384 + ct * 32 + tx];
  __syncthreads();
#pragma unroll
  for (int i = 0; i < 4; ++i)
    dst[(size_t)(ct * 32 + ty + 8 * i) * NPOINT + jt * 32 + tx] = tile[tx][ty + 8 * i];
}

extern "C" void kernel_launch(void* const* d_in, const int* in_sizes, int n_in,
                              void* d_out, int out_size, void* d_ws, size_t ws_size,
                              hipStream_t stream) {
  const float* xyz  = (const float*)d_in[0];
  const float* feat = (const float*)d_in[1];
  const float* W1   = (const float*)d_in[2];
  const float* b1   = (const float*)d_in[3];
  const float* W2   = (const float*)d_in[4];
  const float* b2   = (const float*)d_in[5];
  const float* Wcr  = (const float*)d_in[6];
  const float* bcr  = (const float*)d_in[7];
  float* out_xyz  = (float*)d_out;                          // (B, 512, 3)
  float* out_feat = out_xyz + (size_t)BATCH * NPOINT * 3;   // (B, 384, 512)
  float* featT    = (float*)d_ws;                           // (B, N, C) 16 MB
  size_t featT_bytes = (size_t)BATCH * NPTS * CFEAT * sizeof(float);
  size_t tmp_bytes   = (size_t)BATCH * NPOINT * 384 * sizeof(float);

  fps_transpose_kernel<<<BATCH + BATCH * 256, 256, 0, stream>>>(xyz, feat, featT, out_xyz);

  if (ws_size >= featT_bytes + tmp_bytes) {
    float* tmp = (float*)((char*)d_ws + featT_bytes);       // (B, 512, 384)
    center_kernel<<<dim3(NPOINT, BATCH), 128, 0, stream>>>(
        xyz, featT, W1, b1, W2, b2, Wcr, bcr, (const float*)d_out, out_feat, tmp);
    untranspose_kernel<<<dim3(NPOINT / 32, 384 / 32, BATCH), 256, 0, stream>>>(
        tmp, out_feat);
  } else {
    center_kernel<<<dim3(NPOINT, BATCH), 128, 0, stream>>>(
        xyz, featT, W1, b1, W2, b2, Wcr, bcr, (const float*)d_out, out_feat, nullptr);
  }
}

// Round 11
// 488.549 us; speedup vs baseline: 1.5303x; 1.5303x over previous
//
#include <hip/hip_runtime.h>
#include <hip/hip_bf16.h>

#define BATCH   16
#define NPTS    2048
#define NPOINT  512
#define CFEAT   128
#define CIN     131
#define CMID    32
#define NS_TOT  96

typedef float v2f __attribute__((ext_vector_type(2)));

// exact (non-contracted) squared distance, matching jnp's ((dx^2+dy^2)+dz^2)
__device__ __forceinline__ float d2_rn(float ax, float ay, float az,
                                       float bx, float by, float bz) {
  float dx = __fsub_rn(ax, bx), dy = __fsub_rn(ay, by), dz = __fsub_rn(az, bz);
  return __fadd_rn(__fadd_rn(__fmul_rn(dx, dx), __fmul_rn(dy, dy)), __fmul_rn(dz, dz));
}

// 64-bit packed-key wave max via DPP on both halves. After the 6 steps,
// lane 63 holds the wave max. Key = (dist_bits << 32) | (0xFFF - n):
// max by distance, then smallest index n on ties — matches jnp argmax.
__device__ __forceinline__ unsigned long long wave_kmax64(unsigned long long k) {
#define KSTEP(CTRL, RMASK, BMASK)                                              \
  {                                                                            \
    unsigned hi = (unsigned)(k >> 32), lo = (unsigned)k;                       \
    unsigned thi = (unsigned)__builtin_amdgcn_update_dpp(                      \
        (int)hi, (int)hi, CTRL, RMASK, BMASK, false);                          \
    unsigned tlo = (unsigned)__builtin_amdgcn_update_dpp(                      \
        (int)lo, (int)lo, CTRL, RMASK, BMASK, false);                          \
    unsigned long long tk = ((unsigned long long)thi << 32) | tlo;             \
    k = tk > k ? tk : k;                                                       \
  }
  KSTEP(0x111, 0xf, 0xf)  // row_shr:1
  KSTEP(0x112, 0xf, 0xf)  // row_shr:2
  KSTEP(0x114, 0xf, 0xe)  // row_shr:4
  KSTEP(0x118, 0xf, 0xc)  // row_shr:8
  KSTEP(0x142, 0xa, 0xf)  // row_bcast:15
  KSTEP(0x143, 0xc, 0xf)  // row_bcast:31
#undef KSTEP
  return k;  // valid in lane 63
}

// blocks [0,16): FPS per batch; blocks [16, 16+4096): transpose features -> featT
__global__ __launch_bounds__(256) void fps_transpose_kernel(
    const float* __restrict__ xyz, const float* __restrict__ feat,
    float* __restrict__ featT, float* __restrict__ out_xyz)
{
  int t = threadIdx.x;
  if (blockIdx.x >= BATCH) {
    __shared__ float tile[32][33];
    int m  = blockIdx.x - BATCH;
    int b  = m >> 8;
    int c0 = ((m >> 6) & 3) << 5;
    int n0 = (m & 63) << 5;
    int tx = t & 31, ty = t >> 5;
    const float* src = feat  + (size_t)b * CFEAT * NPTS;
    float*       dst = featT + (size_t)b * NPTS * CFEAT;
#pragma unroll
    for (int i = 0; i < 4; ++i)
      tile[ty + 8 * i][tx] = src[(size_t)(c0 + ty + 8 * i) * NPTS + n0 + tx];
    __syncthreads();
#pragma unroll
    for (int i = 0; i < 4; ++i)
      dst[(size_t)(n0 + ty + 8 * i) * CFEAT + c0 + tx] = tile[tx][ty + 8 * i];
    return;
  }
  // ---- FPS: one block per batch, 256 threads (4 waves), 8 pts/thread.
  // One barrier per step; no global-memory ops inside the step loop.
  // (Round-3 structure, verified at ~239 us across three runs.)
  __shared__ float4 sp[NPTS];               // 32 KB
  __shared__ unsigned long long skey[2][4]; // [parity][wave]
  __shared__ int slast[NPOINT];             // 2 KB: selected index per step
  int b = blockIdx.x;
  const float* xb = xyz + (size_t)b * NPTS * 3;
  for (int n = t; n < NPTS; n += 256) {
    const float* p = xb + n * 3;
    sp[n] = make_float4(p[0], p[1], p[2], 0.f);
  }
  if (t == 0) slast[0] = 0;
  __syncthreads();
  float lx[8], ly[8], lz[8], d[8];
#pragma unroll
  for (int i = 0; i < 8; ++i) {
    float4 q = sp[(i << 8) + t];
    lx[i] = q.x; ly[i] = q.y; lz[i] = q.z;
    d[i] = 1e10f;
  }
  int last = 0;
  int w = t >> 6;
  int tb = 0xFFF - t;
#pragma unroll 1
  for (int step = 1; step < NPOINT; ++step) {
    float4 pv = sp[last];
    unsigned long long best = 0ull;
#pragma unroll
    for (int i = 0; i < 8; ++i) {
      float dd = d2_rn(lx[i], ly[i], lz[i], pv.x, pv.y, pv.z);
      float nd = fminf(d[i], dd);
      d[i] = nd;
      unsigned long long k = ((unsigned long long)__float_as_uint(nd) << 32)
                           | (unsigned)(tb - (i << 8));
      best = (k > best) ? k : best;
    }
    unsigned long long wk = wave_kmax64(best);
    int par = step & 1;
    if ((t & 63) == 63) skey[par][w] = wk;
    __syncthreads();
    unsigned long long k0 = skey[par][0], k1 = skey[par][1];
    unsigned long long k2 = skey[par][2], k3 = skey[par][3];
    unsigned long long ka = k0 > k1 ? k0 : k1;
    unsigned long long kb = k2 > k3 ? k2 : k3;
    unsigned long long km = ka > kb ? ka : kb;
    last = (0xFFF - (int)((unsigned)km & 0xFFFu)) & (NPTS - 1);
    if (t == 0) slast[step] = last;
  }
  __syncthreads();
  for (int s = t; s < NPOINT; s += 256) {
    float4 q = sp[slast[s]];
    float* o = out_xyz + ((size_t)b * NPOINT + s) * 3;
    o[0] = q.x; o[1] = q.y; o[2] = q.z;
  }
}

// one block per (center j, batch b): ball query (3 radii) + MLP + maxpool + GEMM
// out_tmp != nullptr: write (b, j, 384) coalesced; else legacy strided writes.
__global__ __launch_bounds__(128, 4) void center_kernel(
    const float* __restrict__ xyz, const float* __restrict__ featT,
    const float* __restrict__ W1, const float* __restrict__ b1,
    const float* __restrict__ W2, const float* __restrict__ b2,
    const float* __restrict__ Wcr, const float* __restrict__ bcr,
    const float* __restrict__ new_xyz, float* __restrict__ out_feat,
    float* __restrict__ out_tmp)
{
  int j = blockIdx.x, b = blockIdx.y, t = threadIdx.x;
  __shared__ int   sIdx[NS_TOT];
  __shared__ __align__(16) float sH1[NS_TOT * 36];   // stride 36: 16B rows
  __shared__ float sVr[NS_TOT * 4];                  // relu(h2_c * rel_c), c<3
  __shared__ __align__(16) float sPooled[3 * 132];

  float cx = new_xyz[((size_t)b * NPOINT + j) * 3 + 0];
  float cy = new_xyz[((size_t)b * NPOINT + j) * 3 + 1];
  float cz = new_xyz[((size_t)b * NPOINT + j) * 3 + 2];

  // ---- ball query: wave 0 -> r0,r1 ; wave 1 -> r2. Ascending index order. ----
  {
    int w = t >> 6, lane = t & 63;
    const float* xb = xyz + (size_t)b * NPTS * 3;
    unsigned long long lt = (1ull << lane) - 1ull;
    if (w == 0) {
      int c0 = 0, c1 = 0;
      for (int it = 0; it < 32; ++it) {
        int n = (it << 6) + lane;
        float px = xb[n * 3 + 0], py = xb[n * 3 + 1], pz = xb[n * 3 + 2];
        float d2 = d2_rn(cx, cy, cz, px, py, pz);
        bool i0 = d2 < 0.01f, i1 = d2 < 0.04f;
        unsigned long long m0 = __ballot(i0), m1 = __ballot(i1);
        if (i0) { int pos = c0 + __popcll(m0 & lt); if (pos < 16) sIdx[pos] = n; }
        if (i1) { int pos = c1 + __popcll(m1 & lt); if (pos < 32) sIdx[16 + pos] = n; }
        c0 += __popcll(m0); c1 += __popcll(m1);
        if (c0 >= 16 && c1 >= 32) break;
      }
      int f0 = sIdx[0];
      int f1 = sIdx[16];
      if (lane >= c0 && lane < 16) sIdx[lane] = f0;
      if (lane >= c1 && lane < 32) sIdx[16 + lane] = f1;
    } else {
      int c2 = 0;
      for (int it = 0; it < 32; ++it) {
        int n = (it << 6) + lane;
        float px = xb[n * 3 + 0], py = xb[n * 3 + 1], pz = xb[n * 3 + 2];
        float d2 = d2_rn(cx, cy, cz, px, py, pz);
        bool i2 = d2 < 0.16f;
        unsigned long long m2 = __ballot(i2);
        if (i2) { int pos = c2 + __popcll(m2 & lt); if (pos < 48) sIdx[48 + pos] = n; }
        c2 += __popcll(m2);
        if (c2 >= 48) break;
      }
      int f2 = sIdx[48];
      if (lane >= c2 && lane < 48) sIdx[48 + lane] = f2;
    }
  }
  __syncthreads();

  // ---- h1 = relu(h10 @ W1 + b1), packed channel pairs (exact per-channel
  // chain); also rel channels' relu(h2_c * rel_c) ----
  if (t < NS_TOT) {
    int idx = sIdx[t];
    const float* p = xyz + ((size_t)b * NPTS + (size_t)idx) * 3;
    float px = p[0], py = p[1], pz = p[2];
    float rx = __fsub_rn(px, cx), ry = __fsub_rn(py, cy), rz = __fsub_rn(pz, cz);
    float dist = sqrtf(__fadd_rn(__fadd_rn(__fmul_rn(rx, rx), __fmul_rn(ry, ry)),
                                 __fmul_rn(rz, rz)));
    float h10[10] = {dist, cx, cy, cz, px, py, pz, rx, ry, rz};
    float h1r[CMID];
#pragma unroll
    for (int m = 0; m < CMID / 2; ++m) {
      v2f a = { b1[2 * m], b1[2 * m + 1] };
#pragma unroll
      for (int i = 0; i < 10; ++i) {
        v2f wv = { W1[i * CMID + 2 * m], W1[i * CMID + 2 * m + 1] };
        v2f hv = { h10[i], h10[i] };
        a = __builtin_elementwise_fma(hv, wv, a);
      }
      v2f z = { 0.f, 0.f };
      a = __builtin_elementwise_max(a, z);
      h1r[2 * m] = a.x; h1r[2 * m + 1] = a.y;
    }
#pragma unroll
    for (int q = 0; q < 8; ++q)
      *(float4*)&sH1[t * 36 + 4 * q] = *(const float4*)&h1r[4 * q];
    v2f pa0 = { b2[0], 0.f }, pa1 = { b2[1], 0.f }, pa2 = { b2[2], 0.f };
#pragma unroll
    for (int m = 0; m < CMID / 2; ++m) {
      v2f hv = { h1r[2 * m], h1r[2 * m + 1] };
      v2f w0 = { W2[(2 * m) * CIN + 0], W2[(2 * m + 1) * CIN + 0] };
      v2f w1 = { W2[(2 * m) * CIN + 1], W2[(2 * m + 1) * CIN + 1] };
      v2f w2 = { W2[(2 * m) * CIN + 2], W2[(2 * m + 1) * CIN + 2] };
      pa0 = __builtin_elementwise_fma(hv, w0, pa0);
      pa1 = __builtin_elementwise_fma(hv, w1, pa1);
      pa2 = __builtin_elementwise_fma(hv, w2, pa2);
    }
    float a0 = __fadd_rn(pa0.x, pa0.y);
    float a1 = __fadd_rn(pa1.x, pa1.y);
    float a2 = __fadd_rn(pa2.x, pa2.y);
    sVr[t * 4 + 0] = fmaxf(__fmul_rn(a0, rx), 0.f);
    sVr[t * 4 + 1] = fmaxf(__fmul_rn(a1, ry), 0.f);
    sVr[t * 4 + 2] = fmaxf(__fmul_rn(a2, rz), 0.f);
  }
  __syncthreads();

  // ---- feature channels, s-split: wave0 -> samples 0..47 (r0,r1), wave1 ->
  // samples 48..95 (r2). Each lane covers channels (lane, lane+64).
  // unroll 2: double the outstanding featT gathers (latency cover). ----
  {
    int w = t >> 6, lane = t & 63;
    v2f wA[16], wB[16];
#pragma unroll
    for (int m = 0; m < 16; ++m) {
      wA[m] = (v2f){ W2[(2 * m) * CIN + 3 + lane],
                     W2[(2 * m + 1) * CIN + 3 + lane] };
      wB[m] = (v2f){ W2[(2 * m) * CIN + 3 + lane + 64],
                     W2[(2 * m + 1) * CIN + 3 + lane + 64] };
    }
    float bA = b2[3 + lane], bB = b2[3 + lane + 64];
    const float* ftb = featT + (size_t)b * NPTS * CFEAT;
    int sBeg = w ? 48 : 0;
    int sEnd = w ? 96 : 48;
    int sMid = w ? 10000 : 16;   // wave0 stores r0 row after s==15
    float xA0 = ftb[(size_t)sIdx[sBeg] * CFEAT + lane];
    float xB0 = ftb[(size_t)sIdx[sBeg] * CFEAT + lane + 64];
    float xA1 = ftb[(size_t)sIdx[sBeg + 1] * CFEAT + lane];
    float xB1 = ftb[(size_t)sIdx[sBeg + 1] * CFEAT + lane + 64];
    float plA = 0.f, plB = 0.f;
#pragma unroll 2
    for (int s = sBeg; s < sEnd; ++s) {
      int sp2 = (s + 2 < sEnd) ? s + 2 : sEnd - 1;
      float xA2 = ftb[(size_t)sIdx[sp2] * CFEAT + lane];
      float xB2 = ftb[(size_t)sIdx[sp2] * CFEAT + lane + 64];
      const float4* h4 = (const float4*)&sH1[s * 36];
      v2f aAA = (v2f){ bA, 0.f }, aAB = (v2f){ 0.f, 0.f };
      v2f aBA = (v2f){ bB, 0.f }, aBB = (v2f){ 0.f, 0.f };
#pragma unroll
      for (int q = 0; q < 8; ++q) {
        float4 h = h4[q];
        v2f hxy = (v2f){ h.x, h.y }, hzw = (v2f){ h.z, h.w };
        aAA = __builtin_elementwise_fma(hxy, wA[2 * q],     aAA);
        aAB = __builtin_elementwise_fma(hzw, wA[2 * q + 1], aAB);
        aBA = __builtin_elementwise_fma(hxy, wB[2 * q],     aBA);
        aBB = __builtin_elementwise_fma(hzw, wB[2 * q + 1], aBB);
      }
      float hA = __fadd_rn(__fadd_rn(aAA.x, aAA.y), __fadd_rn(aAB.x, aAB.y));
      float hB = __fadd_rn(__fadd_rn(aBA.x, aBA.y), __fadd_rn(aBB.x, aBB.y));
      plA = fmaxf(plA, fmaxf(__fmul_rn(hA, xA0), 0.f));
      plB = fmaxf(plB, fmaxf(__fmul_rn(hB, xB0), 0.f));
      xA0 = xA1; xA1 = xA2; xB0 = xB1; xB1 = xB2;
      if (s + 1 == sMid) {   // wave0 only: end of r0 segment
        sPooled[0 * 132 + 3 + lane]      = plA;
        sPooled[0 * 132 + 3 + lane + 64] = plB;
        plA = 0.f; plB = 0.f;
      }
    }
    int rowL = w ? 2 : 1;
    sPooled[rowL * 132 + 3 + lane]      = plA;
    sPooled[rowL * 132 + 3 + lane + 64] = plB;
  }
  // ---- rel channels (0..2): segment max over sVr, threads 0..8 ----
  if (t < 9) {
    int r = t / 3, c = t - r * 3;
    int s0 = (r == 0) ? 0 : (r == 1 ? 16 : 48);
    int s1 = (r == 0) ? 16 : (r == 1 ? 48 : 96);
    float pl = 0.f;
    for (int s = s0; s < s1; ++s) pl = fmaxf(pl, sVr[s * 4 + c]);
    sPooled[r * 132 + c] = pl;
  }
  __syncthreads();

  // ---- out = relu(pooled @ Wcr + bcr): radii 0,1 packed, radius 2 scalar.
  // unroll 2: double the outstanding Wcr loads. ----
  v2f s01 = { bcr[t], bcr[t] };
  float s2 = bcr[t];
#pragma unroll 2
  for (int k4 = 0; k4 < 128; k4 += 4) {
    float4 p0 = *(const float4*)&sPooled[k4];
    float4 p1 = *(const float4*)&sPooled[132 + k4];
    float4 p2 = *(const float4*)&sPooled[264 + k4];
#pragma unroll
    for (int u = 0; u < 4; ++u) {
      float w = Wcr[(k4 + u) * CFEAT + t];
      float e0 = (&p0.x)[u], e1 = (&p1.x)[u], e2 = (&p2.x)[u];
      s01 = __builtin_elementwise_fma((v2f){ e0, e1 }, (v2f){ w, w }, s01);
      s2  = fmaf(e2, w, s2);
    }
  }
#pragma unroll
  for (int k = 128; k < CIN; ++k) {
    float w = Wcr[k * CFEAT + t];
    s01 = __builtin_elementwise_fma((v2f){ sPooled[k], sPooled[132 + k] },
                                    (v2f){ w, w }, s01);
    s2  = fmaf(sPooled[264 + k], w, s2);
  }
  if (out_tmp) {
    // coalesced: (b, j, c) with c = r*128 + t -> 3 contiguous 512B stores
    float* ob = out_tmp + ((size_t)b * NPOINT + j) * 384;
    ob[t]       = fmaxf(s01.x, 0.f);
    ob[128 + t] = fmaxf(s01.y, 0.f);
    ob[256 + t] = fmaxf(s2, 0.f);
  } else {
    float* ob = out_feat + (size_t)b * 384 * NPOINT + j;
    ob[(size_t)(0 * CFEAT + t) * NPOINT] = fmaxf(s01.x, 0.f);
    ob[(size_t)(1 * CFEAT + t) * NPOINT] = fmaxf(s01.y, 0.f);
    ob[(size_t)(2 * CFEAT + t) * NPOINT] = fmaxf(s2, 0.f);
  }
}

// tmp (b, j, 384) -> out_feat (b, 384, j): 32x32 LDS tile, both sides coalesced
__global__ __launch_bounds__(256) void untranspose_kernel(
    const float* __restrict__ tmp, float* __restrict__ out_feat)
{
  __shared__ float tile[32][33];
  int jt = blockIdx.x, ct = blockIdx.y, b = blockIdx.z;
  int t = threadIdx.x, tx = t & 31, ty = t >> 5;
  const float* src = tmp      + (size_t)b * NPOINT * 384;
  float*       dst = out_feat + (size_t)b * 384 * NPOINT;
#pragma unroll
  for (int i = 0; i < 4; ++i)
    tile[ty + 8 * i][tx] = src[(size_t)(jt * 32 + ty + 8 * i) * 384 + ct * 32 + tx];
  __syncthreads();
#pragma unroll
  for (int i = 0; i < 4; ++i)
    dst[(size_t)(ct * 32 + ty + 8 * i) * NPOINT + jt * 32 + tx] = tile[tx][ty + 8 * i];
}

extern "C" void kernel_launch(void* const* d_in, const int* in_sizes, int n_in,
                              void* d_out, int out_size, void* d_ws, size_t ws_size,
                              hipStream_t stream) {
  const float* xyz  = (const float*)d_in[0];
  const float* feat = (const float*)d_in[1];
  const float* W1   = (const float*)d_in[2];
  const float* b1   = (const float*)d_in[3];
  const float* W2   = (const float*)d_in[4];
  const float* b2   = (const float*)d_in[5];
  const float* Wcr  = (const float*)d_in[6];
  const float* bcr  = (const float*)d_in[7];
  float* out_xyz  = (float*)d_out;                          // (B, 512, 3)
  float* out_feat = out_xyz + (size_t)BATCH * NPOINT * 3;   // (B, 384, 512)
  float* featT    = (float*)d_ws;                           // (B, N, C) 16 MB
  size_t featT_bytes = (size_t)BATCH * NPTS * CFEAT * sizeof(float);
  size_t tmp_bytes   = (size_t)BATCH * NPOINT * 384 * sizeof(float);

  fps_transpose_kernel<<<BATCH + BATCH * 256, 256, 0, stream>>>(xyz, feat, featT, out_xyz);

  if (ws_size >= featT_bytes + tmp_bytes) {
    float* tmp = (float*)((char*)d_ws + featT_bytes);       // (B, 512, 384)
    center_kernel<<<dim3(NPOINT, BATCH), 128, 0, stream>>>(
        xyz, featT, W1, b1, W2, b2, Wcr, bcr, (const float*)d_out, out_feat, tmp);
    untranspose_kernel<<<dim3(NPOINT / 32, 384 / 32, BATCH), 256, 0, stream>>>(
        tmp, out_feat);
  } else {
    center_kernel<<<dim3(NPOINT, BATCH), 128, 0, stream>>>(
        xyz, featT, W1, b1, W2, b2, Wcr, bcr, (const float*)d_out, out_feat, nullptr);
  }
}